// Round 12
// baseline (402.563 us; speedup 1.0000x reference)
//
#include <hip/hip_runtime.h>
#include <hip/hip_bf16.h>

#define FI 64
#define FO 63
#define FP 64
#define NZPW 8
#define INV_TAU 20.0f
#define LOG2E 1.4426950408889634f
#define CHUNK 4096
#define SCAP 12288   // kb_sort LDS staging capacity (96KB)

// raw gfx950 transcendentals: v_exp_f32 = 2^x, v_log_f32 = log2(x).
__device__ __forceinline__ float fexp2(float x) {
    float y; asm("v_exp_f32 %0, %1" : "=v"(y) : "v"(x)); return y;
}
__device__ __forceinline__ float flog2(float x) {
    float y; asm("v_log_f32 %0, %1" : "=v"(y) : "v"(x)); return y;
}

// ---------------- MLP (n_func): x (n,64) -> x1 padded (n,64) ----------------
__global__ __launch_bounds__(256) void k_mlp_n(
    const float* __restrict__ x,
    const float* __restrict__ W1, const float* __restrict__ b1,
    const float* __restrict__ W2, const float* __restrict__ b2,
    float* __restrict__ x1p, int n)
{
    int t = blockIdx.x * 256 + threadIdx.x;
    if (t >= n) return;
    const float* xr = x + (size_t)t * FI;

    float h[FO];
#pragma unroll
    for (int j = 0; j < FO; ++j) h[j] = b1[j];
#pragma unroll 1
    for (int ii = 0; ii < FI; ii += 4) {
        float4 xq = *(const float4*)(xr + ii);
#pragma unroll
        for (int j = 0; j < FO; ++j) h[j] = fmaf(xq.x, W1[(ii+0)*FO+j], h[j]);
#pragma unroll
        for (int j = 0; j < FO; ++j) h[j] = fmaf(xq.y, W1[(ii+1)*FO+j], h[j]);
#pragma unroll
        for (int j = 0; j < FO; ++j) h[j] = fmaf(xq.z, W1[(ii+2)*FO+j], h[j]);
#pragma unroll
        for (int j = 0; j < FO; ++j) h[j] = fmaf(xq.w, W1[(ii+3)*FO+j], h[j]);
    }
#pragma unroll
    for (int j = 0; j < FO; ++j) h[j] = fmaxf(h[j], 0.f);

    float o[FO];
#pragma unroll
    for (int j = 0; j < FO; ++j) o[j] = b2[j];
#pragma unroll 1
    for (int i = 0; i < FO; ++i) {
        float hi = h[i];
#pragma unroll
        for (int j = 0; j < FO; ++j) o[j] = fmaf(hi, W2[i*FO+j], o[j]);
    }

    float* dst = x1p + (size_t)t * FP;
#pragma unroll
    for (int c = 0; c < 15; ++c) {
        float4 w;
        w.x = fmaxf(o[4*c+0], 0.f);
        w.y = fmaxf(o[4*c+1], 0.f);
        w.z = fmaxf(o[4*c+2], 0.f);
        w.w = fmaxf(o[4*c+3], 0.f);
        ((float4*)dst)[c] = w;
    }
    {
        float4 w;
        w.x = fmaxf(o[60], 0.f);
        w.y = fmaxf(o[61], 0.f);
        w.z = fmaxf(o[62], 0.f);
        w.w = 0.f;
        ((float4*)dst)[15] = w;
    }
}

// ------------- 256-bin histogram over both matrices (bucket = row>>8) -------
__global__ __launch_bounds__(256) void k_hist256(
    const int* __restrict__ rowsK, const int* __restrict__ rowsA,
    int* __restrict__ cntK, int* __restrict__ cntA, int nnzK, int nnzA)
{
    __shared__ int h[512];
    int tid = threadIdx.x;
    h[tid] = 0; h[tid + 256] = 0;
    __syncthreads();
    int i = blockIdx.x * 256 + tid;
    int stride = gridDim.x * 256;
    int total = nnzK + nnzA;
    for (; i < total; i += stride) {
        if (i < nnzK) atomicAdd(&h[rowsK[i] >> 8], 1);
        else          atomicAdd(&h[256 + (rowsA[i - nnzK] >> 8)], 1);
    }
    __syncthreads();
    if (h[tid])       atomicAdd(&cntK[tid], h[tid]);
    if (h[tid + 256]) atomicAdd(&cntA[tid], h[tid + 256]);
}

// ------------- scan 256 counts -> bstart[257] and gcur cursors (1 block) ----
__global__ __launch_bounds__(256) void k_scan256(
    const int* __restrict__ cntK, const int* __restrict__ cntA,
    int* __restrict__ bstartK, int* __restrict__ gcurK,
    int* __restrict__ bstartA, int* __restrict__ gcurA)
{
    __shared__ int tmp[256];
    int t = threadIdx.x;
    int c = cntK[t];
    tmp[t] = c; __syncthreads();
#pragma unroll 1
    for (int off = 1; off < 256; off <<= 1) {
        int v = (t >= off) ? tmp[t - off] : 0;
        __syncthreads();
        tmp[t] += v;
        __syncthreads();
    }
    bstartK[t + 1] = tmp[t];
    gcurK[t] = tmp[t] - c;
    if (t == 0) bstartK[0] = 0;
    __syncthreads();
    c = cntA[t];
    tmp[t] = c; __syncthreads();
#pragma unroll 1
    for (int off = 1; off < 256; off <<= 1) {
        int v = (t >= off) ? tmp[t - off] : 0;
        __syncthreads();
        tmp[t] += v;
        __syncthreads();
    }
    bstartA[t + 1] = tmp[t];
    gcurA[t] = tmp[t] - c;
    if (t == 0) bstartA[0] = 0;
}

// ------------- bucket pass: block-local LDS counting sort, run-copied out ---
__global__ __launch_bounds__(256) void kb_bucket(
    const int* __restrict__ rows, const int* __restrict__ cols,
    const float* __restrict__ val, int* __restrict__ gcur,
    int2* __restrict__ sdat, int nnz)
{
    __shared__ int cnt[256], loff[256], cnt2[256], shiftv[256];
    __shared__ int sm_meta[CHUNK];
    __shared__ float sm_val[CHUNK];
    __shared__ unsigned char sm_bid[CHUNK];
    int tid = threadIdx.x;
    int i0 = blockIdx.x * CHUNK;
    int i1 = min(i0 + CHUNK, nnz);
    int m = i1 - i0;

    cnt[tid] = 0; cnt2[tid] = 0;
    __syncthreads();
#pragma unroll 1
    for (int i = i0 + tid; i < i1; i += 256)
        atomicAdd(&cnt[rows[i] >> 8], 1);
    __syncthreads();
    loff[tid] = cnt[tid];
    __syncthreads();
#pragma unroll 1
    for (int off = 1; off < 256; off <<= 1) {
        int v = (tid >= off) ? loff[tid - off] : 0;
        __syncthreads();
        loff[tid] += v;
        __syncthreads();
    }
    int excl = loff[tid] - cnt[tid];
    __syncthreads();
    loff[tid] = excl;
    int gb = cnt[tid] ? atomicAdd(&gcur[tid], cnt[tid]) : 0;
    shiftv[tid] = gb - excl;
    __syncthreads();
#pragma unroll 1
    for (int i = i0 + tid; i < i1; i += 256) {
        int r = rows[i];
        int b = r >> 8;
        int s = loff[b] + atomicAdd(&cnt2[b], 1);
        sm_meta[s] = cols[i] | ((r & 255) << 16);
        sm_val[s]  = val[i];
        sm_bid[s]  = (unsigned char)b;
    }
    __syncthreads();
#pragma unroll 1
    for (int s = tid; s < m; s += 256) {
        int b = sm_bid[s];
        sdat[shiftv[b] + s] = make_int2(sm_meta[s], __float_as_int(sm_val[s]));
    }
}

// ------------- kb_sort: per-bucket LDS row-sort + per-row ptr ---------------
__global__ __launch_bounds__(256) void kb_sort(
    const int* __restrict__ bstart, int2* __restrict__ sdat,
    int* __restrict__ ptr, int2* __restrict__ scratch)
{
    __shared__ int cnt[256], off[256], cur[256];
    __shared__ int2 stage[SCAP];
    int tid = threadIdx.x;
    int b = blockIdx.x;
    int s = bstart[b], e = bstart[b + 1];
    int m = e - s;
    cnt[tid] = 0;
    __syncthreads();
    bool fits = (m <= SCAP);
    if (fits) {
#pragma unroll 1
        for (int i = tid; i < m; i += 256) {
            int2 d = sdat[s + i];
            stage[i] = d;
            atomicAdd(&cnt[(d.x >> 16) & 255], 1);
        }
    } else {
#pragma unroll 1
        for (int i = tid; i < m; i += 256) {
            int2 d = sdat[s + i];
            scratch[s + i] = d;
            atomicAdd(&cnt[(d.x >> 16) & 255], 1);
        }
    }
    __syncthreads();
    int c = cnt[tid];
    off[tid] = c;
    __syncthreads();
#pragma unroll 1
    for (int o = 1; o < 256; o <<= 1) {
        int v = (tid >= o) ? off[tid - o] : 0;
        __syncthreads();
        off[tid] += v;
        __syncthreads();
    }
    ptr[b * 256 + tid] = s + off[tid];
    cur[tid] = off[tid] - c;
    __syncthreads();
    if (fits) {
#pragma unroll 1
        for (int i = tid; i < m; i += 256) {
            int2 d = stage[i];
            int p = atomicAdd(&cur[(d.x >> 16) & 255], 1);
            sdat[s + p] = d;
        }
    } else {
        __threadfence();
        __syncthreads();
#pragma unroll 1
        for (int i = tid; i < m; i += 256) {
            int2 d = scratch[s + i];
            int p = atomicAdd(&cur[(d.x >> 16) & 255], 1);
            sdat[s + p] = d;
        }
    }
}

// ------------- gather spmm on packed sorted data (col in low 16 bits) -------
__global__ __launch_bounds__(256) void kb_gather(
    const int* __restrict__ ptr, const int2* __restrict__ sdat,
    const float* __restrict__ xin,
    float* __restrict__ out, int n)
{
    int r = blockIdx.x * 4 + (threadIdx.x >> 6);
    int lane = threadIdx.x & 63;
    if (r >= n) return;
    int s = (r == 0) ? 0 : ptr[r - 1];
    int e = ptr[r];
    float acc = 0.f;
    int k = s;
#pragma unroll 1
    for (; k + 3 < e; k += 4) {
        int2 d0 = sdat[k],     d1 = sdat[k + 1];
        int2 d2 = sdat[k + 2], d3 = sdat[k + 3];
        float x0 = xin[((d0.x & 0xFFFF) << 6) + lane];
        float x1 = xin[((d1.x & 0xFFFF) << 6) + lane];
        float x2 = xin[((d2.x & 0xFFFF) << 6) + lane];
        float x3 = xin[((d3.x & 0xFFFF) << 6) + lane];
        acc = fmaf(__int_as_float(d0.y), x0, acc);
        acc = fmaf(__int_as_float(d1.y), x1, acc);
        acc = fmaf(__int_as_float(d2.y), x2, acc);
        acc = fmaf(__int_as_float(d3.y), x3, acc);
    }
#pragma unroll 1
    for (; k < e; ++k) {
        int2 d0 = sdat[k];
        acc = fmaf(__int_as_float(d0.y), xin[((d0.x & 0xFFFF) << 6) + lane], acc);
    }
    out[((size_t)r << 6) + lane] = acc;
}

// ---------------- tier-2 sequential CSR helpers (proven fallback) -----------
__global__ __launch_bounds__(256) void k_hist(
    const int* __restrict__ rows, int* __restrict__ cnt, int nnz)
{
    int i = blockIdx.x * 256 + threadIdx.x;
    int stride = gridDim.x * 256;
    for (; i < nnz; i += stride) atomicAdd(&cnt[rows[i]], 1);
}

__global__ __launch_bounds__(1024) void k_scan2(
    int* __restrict__ ptrK, int* __restrict__ ptrA)
{
    __shared__ int tot[1024];
    int* ptr = (blockIdx.x == 0) ? ptrK : ptrA;
    int t = threadIdx.x;
    int4* p4 = (int4*)(ptr + t * 64);
    int sum = 0;
#pragma unroll 1
    for (int q = 0; q < 16; ++q) {
        int4 b = p4[q];
        sum += b.x + b.y + b.z + b.w;
    }
    tot[t] = sum;
    __syncthreads();
#pragma unroll 1
    for (int off = 1; off < 1024; off <<= 1) {
        int v2 = 0;
        if (t >= off) v2 = tot[t - off];
        __syncthreads();
        if (t >= off) tot[t] += v2;
        __syncthreads();
    }
    int off = (t == 0) ? 0 : tot[t - 1];
#pragma unroll 1
    for (int q = 0; q < 16; ++q) {
        int4 b = p4[q];
        int4 w;
        w.x = off; off += b.x;
        w.y = off; off += b.y;
        w.z = off; off += b.z;
        w.w = off; off += b.w;
        p4[q] = w;
    }
}

__global__ __launch_bounds__(256) void k_scatter(
    const int* __restrict__ rows, const int* __restrict__ cols,
    const float* __restrict__ val, int* __restrict__ ptr,
    int2* __restrict__ sdat, int nnz)
{
    int i = blockIdx.x * 256 + threadIdx.x;
    int stride = gridDim.x * 256;
    for (; i < nnz; i += stride) {
        int p = atomicAdd(&ptr[rows[i]], 1);
        sdat[p] = make_int2(cols[i], __float_as_int(val[i]));
    }
}

__global__ __launch_bounds__(256) void k_gather(
    const int* __restrict__ ptr, const int2* __restrict__ sdat,
    const float* __restrict__ xin,
    float* __restrict__ out, int n)
{
    int r = blockIdx.x * 4 + (threadIdx.x >> 6);
    int lane = threadIdx.x & 63;
    if (r >= n) return;
    int s = (r == 0) ? 0 : ptr[r - 1];
    int e = ptr[r];
    float acc = 0.f;
    int k = s;
#pragma unroll 1
    for (; k + 3 < e; k += 4) {
        int2 d0 = sdat[k],     d1 = sdat[k + 1];
        int2 d2 = sdat[k + 2], d3 = sdat[k + 3];
        float x0 = xin[((size_t)d0.x << 6) + lane];
        float x1 = xin[((size_t)d1.x << 6) + lane];
        float x2 = xin[((size_t)d2.x << 6) + lane];
        float x3 = xin[((size_t)d3.x << 6) + lane];
        acc = fmaf(__int_as_float(d0.y), x0, acc);
        acc = fmaf(__int_as_float(d1.y), x1, acc);
        acc = fmaf(__int_as_float(d2.y), x2, acc);
        acc = fmaf(__int_as_float(d3.y), x3, acc);
    }
#pragma unroll 1
    for (; k < e; ++k) {
        int2 d0 = sdat[k];
        acc = fmaf(__int_as_float(d0.y), xin[((size_t)d0.x << 6) + lane], acc);
    }
    out[((size_t)r << 6) + lane] = acc;
}

// ---------------- tier-3 fallback spmm: COO scatter-atomic ------------------
__global__ __launch_bounds__(256) void k_spmm(
    const int* __restrict__ rows, const int* __restrict__ cols,
    const float* __restrict__ val, const float* __restrict__ xin,
    float* __restrict__ acc, int nnz)
{
    int wave = blockIdx.x * 4 + (threadIdx.x >> 6);
    int lane = threadIdx.x & 63;
    int e0 = wave * NZPW;
#pragma unroll 1
    for (int k = 0; k < NZPW; ++k) {
        int e = e0 + k;
        if (e >= nnz) break;
        int r = rows[e];
        int c = cols[e];
        float v = val[e];
        float xv = xin[((size_t)c << 6) + lane];
        unsafeAtomicAdd(&acc[((size_t)r << 6) + lane], v * xv);
    }
}

// ------- combine: recompute self-MLP, add spmm2 result, classifier dot ------
__global__ __launch_bounds__(256) void k_combine(
    const float* __restrict__ x,
    const float* __restrict__ W1, const float* __restrict__ b1,
    const float* __restrict__ W2, const float* __restrict__ b2,
    const float* __restrict__ Wc, const float* __restrict__ bcp,
    const float* __restrict__ x2b,
    float* __restrict__ out, float* __restrict__ x3, int n)
{
    int t = blockIdx.x * 256 + threadIdx.x;
    if (t >= n) return;
    const float* xr = x + (size_t)t * FI;

    float h[FO];
#pragma unroll
    for (int j = 0; j < FO; ++j) h[j] = b1[j];
#pragma unroll 1
    for (int ii = 0; ii < FI; ii += 4) {
        float4 xq = *(const float4*)(xr + ii);
#pragma unroll
        for (int j = 0; j < FO; ++j) h[j] = fmaf(xq.x, W1[(ii+0)*FO+j], h[j]);
#pragma unroll
        for (int j = 0; j < FO; ++j) h[j] = fmaf(xq.y, W1[(ii+1)*FO+j], h[j]);
#pragma unroll
        for (int j = 0; j < FO; ++j) h[j] = fmaf(xq.z, W1[(ii+2)*FO+j], h[j]);
#pragma unroll
        for (int j = 0; j < FO; ++j) h[j] = fmaf(xq.w, W1[(ii+3)*FO+j], h[j]);
    }
#pragma unroll
    for (int j = 0; j < FO; ++j) h[j] = fmaxf(h[j], 0.f);

    float o[FO];
#pragma unroll
    for (int j = 0; j < FO; ++j) o[j] = b2[j];
#pragma unroll 1
    for (int i = 0; i < FO; ++i) {
        float hi = h[i];
#pragma unroll
        for (int j = 0; j < FO; ++j) o[j] = fmaf(hi, W2[i*FO+j], o[j]);
    }

    const float4* q4 = (const float4*)(x2b + (size_t)t * FP);
    float4* dst = (float4*)(out + (size_t)t * FP);
    float dot = 0.f;
#pragma unroll
    for (int c = 0; c < 15; ++c) {
        float4 q = q4[c];
        float4 w;
        w.x = q.x + fmaxf(o[4*c+0], 0.f);
        w.y = q.y + fmaxf(o[4*c+1], 0.f);
        w.z = q.z + fmaxf(o[4*c+2], 0.f);
        w.w = q.w + fmaxf(o[4*c+3], 0.f);
        dot = fmaf(w.x, Wc[4*c+0], dot);
        dot = fmaf(w.y, Wc[4*c+1], dot);
        dot = fmaf(w.z, Wc[4*c+2], dot);
        dot = fmaf(w.w, Wc[4*c+3], dot);
        dst[c] = w;
    }
    {
        float4 q = q4[15];
        float4 w;
        w.x = q.x + fmaxf(o[60], 0.f);
        w.y = q.y + fmaxf(o[61], 0.f);
        w.z = q.z + fmaxf(o[62], 0.f);
        w.w = 0.f;
        dot = fmaf(w.x, Wc[60], dot);
        dot = fmaf(w.y, Wc[61], dot);
        dot = fmaf(w.z, Wc[62], dot);
        dst[15] = w;
    }
    x3[t] = dot + bcp[0];
}

// ---------------- sinkhorn v8: wave-owned rows ------------------------------
// Wave w owns rows 16w..16w+15; lane l owns cols 4l..4l+3 (u[16][4], float4
// coalesced). Row normalization (odd iters) = wave-local shfl butterfly:
// ZERO barriers, zero LDS; row offsets R[16] live in registers. Column
// normalization (even iters) = LDS partials + 256-thread reduce (2 barriers).
// Math identical to validated v6: max-tracked iters 0,1; prev-offset 2..19.
// Barriers: 40 (v6) -> 22. u stays read-only (no AGPR write-backs).
__global__ __launch_bounds__(1024) __attribute__((amdgpu_waves_per_eu(4, 4)))
void k_sinkhorn(const float* __restrict__ x3, float* __restrict__ out)
{
    __shared__ float pm[16][264];     // column (m) partials, iter 0
    __shared__ float ps[16][264];     // column (s) partials, even iters
    __shared__ float Cl[256];         // column offsets
    __shared__ float ldspad[12800];   // pad LDS >80KB: 1 block/CU reg budget
    const int tid = threadIdx.x;
    const int w = tid >> 6;           // wave: rows 16w..16w+15
    const int l = tid & 63;           // lane: cols 4l..4l+3

    float u[16][4];
    float R[16];
    const float sc = INV_TAU * LOG2E;
#pragma unroll
    for (int i = 0; i < 16; ++i) {
        float4 a0 = *(const float4*)(x3 + (w*16 + i)*256 + l*4);
        u[i][0] = a0.x*sc; u[i][1] = a0.y*sc; u[i][2] = a0.z*sc; u[i][3] = a0.w*sc;
        R[i] = 0.f;
    }
    if (tid < 256) Cl[tid] = 0.f;
    if (__float_as_int(x3[0]) == 0x7f7f7f7f) ldspad[tid] = 0.f;  // keep pad alive
    __syncthreads();

    // ---- iter 0 (even: LSE over rows a, per column b) — max-tracked ----
    {
        float sm[4], ss[4];
#pragma unroll
        for (int j = 0; j < 4; ++j) {
            float m = u[0][j];
#pragma unroll
            for (int i = 1; i < 16; ++i) m = fmaxf(m, u[i][j]);
            float s = 0.f;
#pragma unroll
            for (int i = 0; i < 16; ++i) s += fexp2(u[i][j] - m);
            sm[j] = m; ss[j] = s;
        }
        *(float4*)&pm[w][l*4] = make_float4(sm[0], sm[1], sm[2], sm[3]);
        *(float4*)&ps[w][l*4] = make_float4(ss[0], ss[1], ss[2], ss[3]);
        __syncthreads();
        if (tid < 256) {
            float M = pm[0][tid], S = ps[0][tid];
#pragma unroll
            for (int k2 = 1; k2 < 16; ++k2) {
                float m2 = pm[k2][tid], s2 = ps[k2][tid];
                float nm = fmaxf(M, m2);
                S = S * fexp2(M - nm) + s2 * fexp2(m2 - nm);
                M = nm;
            }
            Cl[tid] = M + flog2(S);
        }
        __syncthreads();
    }

    // ---- iter 1 (odd: LSE over cols b, per row a) — max-tracked, shfl ----
    {
        float c0 = Cl[l*4+0], c1 = Cl[l*4+1], c2 = Cl[l*4+2], c3 = Cl[l*4+3];
#pragma unroll
        for (int i = 0; i < 16; ++i) {
            float t0 = u[i][0]-c0, t1 = u[i][1]-c1;
            float t2 = u[i][2]-c2, t3 = u[i][3]-c3;
            float m = fmaxf(fmaxf(t0, t1), fmaxf(t2, t3));
#pragma unroll
            for (int d = 1; d < 64; d <<= 1) m = fmaxf(m, __shfl_xor(m, d));
            float s = fexp2(t0-m) + fexp2(t1-m) + fexp2(t2-m) + fexp2(t3-m);
#pragma unroll
            for (int d = 1; d < 64; d <<= 1) s += __shfl_xor(s, d);
            R[i] = m + flog2(s);
        }
    }
    // no barrier needed: iter 1 touches no LDS, Cl unchanged

    // ---- iters 2..19: prev-offset single pass ----
#pragma unroll 1
    for (int it = 2; it < 20; ++it) {
        float c0 = Cl[l*4+0], c1 = Cl[l*4+1], c2 = Cl[l*4+2], c3 = Cl[l*4+3];
        if ((it & 1) == 0) {
            // new C[b] = C_old[b] + log2( sum_a 2^(u - R[a] - C_old[b]) )
            float s0 = 0.f, s1 = 0.f, s2 = 0.f, s3 = 0.f;
#pragma unroll
            for (int i = 0; i < 16; ++i) {
                float ri = R[i];
                s0 += fexp2(u[i][0] - ri - c0);
                s1 += fexp2(u[i][1] - ri - c1);
                s2 += fexp2(u[i][2] - ri - c2);
                s3 += fexp2(u[i][3] - ri - c3);
            }
            *(float4*)&ps[w][l*4] = make_float4(s0, s1, s2, s3);
            __syncthreads();
            if (tid < 256) {
                float S = ps[0][tid];
#pragma unroll
                for (int k2 = 1; k2 < 16; ++k2) S += ps[k2][tid];
                Cl[tid] += flog2(S);
            }
            __syncthreads();
        } else {
            // new R[a] = R_old[a] + log2( sum_b 2^(u - C[b] - R_old[a]) )
#pragma unroll
            for (int i = 0; i < 16; ++i) {
                float ri = R[i];
                float s = fexp2(u[i][0]-c0-ri) + fexp2(u[i][1]-c1-ri)
                        + fexp2(u[i][2]-c2-ri) + fexp2(u[i][3]-c3-ri);
#pragma unroll
                for (int d = 1; d < 64; d <<= 1) s += __shfl_xor(s, d);
                R[i] += flog2(s);
            }
        }
    }

    // ---- output: exp2(u - R - C) ----
    {
        float c0 = Cl[l*4+0], c1 = Cl[l*4+1], c2 = Cl[l*4+2], c3 = Cl[l*4+3];
#pragma unroll
        for (int i = 0; i < 16; ++i) {
            int a = w*16 + i;
            size_t base = ((size_t)(a*256 + l*4) << 6) + 63;
            float ri = R[i];
            out[base]       = fexp2(u[i][0] - ri - c0);
            out[base + 64]  = fexp2(u[i][1] - ri - c1);
            out[base + 128] = fexp2(u[i][2] - ri - c2);
            out[base + 192] = fexp2(u[i][3] - ri - c3);
        }
    }
}

extern "C" void kernel_launch(void* const* d_in, const int* in_sizes, int n_in,
                              void* d_out, int out_size, void* d_ws, size_t ws_size,
                              hipStream_t stream)
{
    const float* K_value = (const float*)d_in[0];
    const int*   K_index = (const int*)d_in[1];
    const float* A_value = (const float*)d_in[2];
    const int*   A_index = (const int*)d_in[3];
    const float* x   = (const float*)d_in[4];
    const float* Wn1 = (const float*)d_in[5];
    const float* bn1 = (const float*)d_in[6];
    const float* Wn2 = (const float*)d_in[7];
    const float* bn2 = (const float*)d_in[8];
    const float* Ws1 = (const float*)d_in[9];
    const float* bs1 = (const float*)d_in[10];
    const float* Ws2 = (const float*)d_in[11];
    const float* bs2 = (const float*)d_in[12];
    const float* Wc  = (const float*)d_in[13];
    const float* bc  = (const float*)d_in[14];

    int nnzK = in_sizes[0];
    int nnzA = in_sizes[2];
    int n    = in_sizes[4] / FI;   // 65536

    const int* rowsK = K_index;  const int* colsK = K_index + nnzK;
    const int* rowsA = A_index;  const int* colsA = A_index + nnzA;

    float* outf = (float*)d_out;
    char*  ws   = (char*)d_ws;
    float* bufA = (float*)ws;                         // 16MB: x1, later x2
    float* x3   = bufA + (size_t)n * FP;              // n floats (tables aliased
    int*   tbl  = (int*)x3;                           //  during build phase)
    int*   cntK = tbl;          int* cntA = tbl + 256;
    int*   bstK = tbl + 512;    int* gcrK = tbl + 772;
    int*   bstA = tbl + 1032;   int* gcrA = tbl + 1292;
    int*   ptrKf = (int*)(x3 + n);                    // n ints
    int*   ptrAf = ptrKf + n;                         // n ints
    int2*  sdatK = (int2*)(ptrAf + n);                // nnzK entries
    int2*  sdatA = sdatK + nnzK;                      // nnzA entries

    size_t need1 = ((size_t)n * FP + 3 * (size_t)n) * 4 + ((size_t)nnzK + nnzA) * 8;
    size_t need2 = ((size_t)n * FP + 2 * (size_t)n) * 4 + (size_t)nnzK * 8;

    // 1. n_func MLP -> bufA (x1, padded to 64)
    k_mlp_n<<<(n + 255) / 256, 256, 0, stream>>>(x, Wn1, bn1, Wn2, bn2, bufA, n);

    if (ws_size >= need1 && n == 65536 && nnzK <= (1 << 24) && nnzA <= (1 << 24)) {
        // ---- tier 1: bucket + LDS row-sort + high-TLP gather ----
        (void)hipMemsetAsync(cntK, 0, 512 * 4, stream);
        k_hist256<<<512, 256, 0, stream>>>(rowsK, rowsA, cntK, cntA, nnzK, nnzA);
        k_scan256<<<1, 256, 0, stream>>>(cntK, cntA, bstK, gcrK, bstA, gcrA);
        kb_bucket<<<(nnzK + CHUNK - 1) / CHUNK, 256, 0, stream>>>(
            rowsK, colsK, K_value, gcrK, sdatK, nnzK);
        kb_bucket<<<(nnzA + CHUNK - 1) / CHUNK, 256, 0, stream>>>(
            rowsA, colsA, A_value, gcrA, sdatA, nnzA);
        kb_sort<<<256, 256, 0, stream>>>(bstK, sdatK, ptrKf, (int2*)outf);
        kb_sort<<<256, 256, 0, stream>>>(bstA, sdatA, ptrAf, (int2*)outf);
        // Wx(d_out) = K @ x1 ; x2(bufA) = A @ Wx
        kb_gather<<<(n + 3) / 4, 256, 0, stream>>>(ptrKf, sdatK, bufA, outf, n);
        kb_gather<<<(n + 3) / 4, 256, 0, stream>>>(ptrAf, sdatA, outf, bufA, n);
    } else if (ws_size >= need2 && n == 65536) {
        // ---- tier 2: sequential CSR (proven) ----
        int* ptrK = (int*)(x3 + n);
        int2* sdat2 = (int2*)(ptrK + n);
        (void)hipMemsetAsync(ptrK, 0, (size_t)n * 4, stream);
        k_hist<<<2048, 256, 0, stream>>>(rowsK, ptrK, nnzK);
        k_scan2<<<1, 1024, 0, stream>>>(ptrK, ptrK);
        k_scatter<<<2048, 256, 0, stream>>>(rowsK, colsK, K_value, ptrK, sdat2, nnzK);
        k_gather<<<(n + 3) / 4, 256, 0, stream>>>(ptrK, sdat2, bufA, outf, n);
        (void)hipMemsetAsync(ptrK, 0, (size_t)n * 4, stream);
        k_hist<<<2048, 256, 0, stream>>>(rowsA, ptrK, nnzA);
        k_scan2<<<1, 1024, 0, stream>>>(ptrK, ptrK);
        k_scatter<<<2048, 256, 0, stream>>>(rowsA, colsA, A_value, ptrK, sdat2, nnzA);
        k_gather<<<(n + 3) / 4, 256, 0, stream>>>(ptrK, sdat2, outf, bufA, n);
    } else {
        // ---- tier 3: atomic scatter fallback ----
        (void)hipMemsetAsync(outf, 0, (size_t)n * FP * 4, stream);
        int blocks1 = (nnzK + 4 * NZPW - 1) / (4 * NZPW);
        k_spmm<<<blocks1, 256, 0, stream>>>(rowsK, colsK, K_value, bufA, outf, nnzK);
        (void)hipMemsetAsync(bufA, 0, (size_t)n * FP * 4, stream);
        int blocks2 = (nnzA + 4 * NZPW - 1) / (4 * NZPW);
        k_spmm<<<blocks2, 256, 0, stream>>>(rowsA, colsA, A_value, outf, bufA, nnzA);
    }

    // combine: self-MLP + x2(bufA), write out[:, :63], classifier -> x3
    k_combine<<<(n + 255) / 256, 256, 0, stream>>>(x, Ws1, bs1, Ws2, bs2, Wc, bc,
                                                   bufA, outf, x3, n);
    // sinkhorn -> out[:, 63]
    k_sinkhorn<<<1, 1024, 0, stream>>>(x3, outf);
}

// Round 13
// 377.564 us; speedup vs baseline: 1.0662x; 1.0662x over previous
//
#include <hip/hip_runtime.h>
#include <hip/hip_bf16.h>

#define FI 64
#define FO 63
#define FP 64
#define NZPW 8
#define INV_TAU 20.0f
#define LOG2E 1.4426950408889634f
#define CHUNK 4096
#define SCAP 12288   // kb_sort LDS staging capacity (96KB)

// raw gfx950 transcendentals: v_exp_f32 = 2^x, v_log_f32 = log2(x).
__device__ __forceinline__ float fexp2(float x) {
    float y; asm("v_exp_f32 %0, %1" : "=v"(y) : "v"(x)); return y;
}
__device__ __forceinline__ float flog2(float x) {
    float y; asm("v_log_f32 %0, %1" : "=v"(y) : "v"(x)); return y;
}

// ---------------- MLP (n_func): x (n,64) -> x1 padded (n,64) ----------------
__global__ __launch_bounds__(256) void k_mlp_n(
    const float* __restrict__ x,
    const float* __restrict__ W1, const float* __restrict__ b1,
    const float* __restrict__ W2, const float* __restrict__ b2,
    float* __restrict__ x1p, int n)
{
    int t = blockIdx.x * 256 + threadIdx.x;
    if (t >= n) return;
    const float* xr = x + (size_t)t * FI;

    float h[FO];
#pragma unroll
    for (int j = 0; j < FO; ++j) h[j] = b1[j];
#pragma unroll 1
    for (int ii = 0; ii < FI; ii += 4) {
        float4 xq = *(const float4*)(xr + ii);
#pragma unroll
        for (int j = 0; j < FO; ++j) h[j] = fmaf(xq.x, W1[(ii+0)*FO+j], h[j]);
#pragma unroll
        for (int j = 0; j < FO; ++j) h[j] = fmaf(xq.y, W1[(ii+1)*FO+j], h[j]);
#pragma unroll
        for (int j = 0; j < FO; ++j) h[j] = fmaf(xq.z, W1[(ii+2)*FO+j], h[j]);
#pragma unroll
        for (int j = 0; j < FO; ++j) h[j] = fmaf(xq.w, W1[(ii+3)*FO+j], h[j]);
    }
#pragma unroll
    for (int j = 0; j < FO; ++j) h[j] = fmaxf(h[j], 0.f);

    float o[FO];
#pragma unroll
    for (int j = 0; j < FO; ++j) o[j] = b2[j];
#pragma unroll 1
    for (int i = 0; i < FO; ++i) {
        float hi = h[i];
#pragma unroll
        for (int j = 0; j < FO; ++j) o[j] = fmaf(hi, W2[i*FO+j], o[j]);
    }

    float* dst = x1p + (size_t)t * FP;
#pragma unroll
    for (int c = 0; c < 15; ++c) {
        float4 w;
        w.x = fmaxf(o[4*c+0], 0.f);
        w.y = fmaxf(o[4*c+1], 0.f);
        w.z = fmaxf(o[4*c+2], 0.f);
        w.w = fmaxf(o[4*c+3], 0.f);
        ((float4*)dst)[c] = w;
    }
    {
        float4 w;
        w.x = fmaxf(o[60], 0.f);
        w.y = fmaxf(o[61], 0.f);
        w.z = fmaxf(o[62], 0.f);
        w.w = 0.f;
        ((float4*)dst)[15] = w;
    }
}

// ------------- 256-bin histogram over both matrices (bucket = row>>8) -------
__global__ __launch_bounds__(256) void k_hist256(
    const int* __restrict__ rowsK, const int* __restrict__ rowsA,
    int* __restrict__ cntK, int* __restrict__ cntA, int nnzK, int nnzA)
{
    __shared__ int h[512];
    int tid = threadIdx.x;
    h[tid] = 0; h[tid + 256] = 0;
    __syncthreads();
    int i = blockIdx.x * 256 + tid;
    int stride = gridDim.x * 256;
    int total = nnzK + nnzA;
    for (; i < total; i += stride) {
        if (i < nnzK) atomicAdd(&h[rowsK[i] >> 8], 1);
        else          atomicAdd(&h[256 + (rowsA[i - nnzK] >> 8)], 1);
    }
    __syncthreads();
    if (h[tid])       atomicAdd(&cntK[tid], h[tid]);
    if (h[tid + 256]) atomicAdd(&cntA[tid], h[tid + 256]);
}

// ------------- scan 256 counts -> bstart[257] and gcur cursors (1 block) ----
__global__ __launch_bounds__(256) void k_scan256(
    const int* __restrict__ cntK, const int* __restrict__ cntA,
    int* __restrict__ bstartK, int* __restrict__ gcurK,
    int* __restrict__ bstartA, int* __restrict__ gcurA)
{
    __shared__ int tmp[256];
    int t = threadIdx.x;
    int c = cntK[t];
    tmp[t] = c; __syncthreads();
#pragma unroll 1
    for (int off = 1; off < 256; off <<= 1) {
        int v = (t >= off) ? tmp[t - off] : 0;
        __syncthreads();
        tmp[t] += v;
        __syncthreads();
    }
    bstartK[t + 1] = tmp[t];
    gcurK[t] = tmp[t] - c;
    if (t == 0) bstartK[0] = 0;
    __syncthreads();
    c = cntA[t];
    tmp[t] = c; __syncthreads();
#pragma unroll 1
    for (int off = 1; off < 256; off <<= 1) {
        int v = (t >= off) ? tmp[t - off] : 0;
        __syncthreads();
        tmp[t] += v;
        __syncthreads();
    }
    bstartA[t + 1] = tmp[t];
    gcurA[t] = tmp[t] - c;
    if (t == 0) bstartA[0] = 0;
}

// ------------- bucket pass: block-local LDS counting sort, run-copied out ---
__global__ __launch_bounds__(256) void kb_bucket(
    const int* __restrict__ rows, const int* __restrict__ cols,
    const float* __restrict__ val, int* __restrict__ gcur,
    int2* __restrict__ sdat, int nnz)
{
    __shared__ int cnt[256], loff[256], cnt2[256], shiftv[256];
    __shared__ int sm_meta[CHUNK];
    __shared__ float sm_val[CHUNK];
    __shared__ unsigned char sm_bid[CHUNK];
    int tid = threadIdx.x;
    int i0 = blockIdx.x * CHUNK;
    int i1 = min(i0 + CHUNK, nnz);
    int m = i1 - i0;

    cnt[tid] = 0; cnt2[tid] = 0;
    __syncthreads();
#pragma unroll 1
    for (int i = i0 + tid; i < i1; i += 256)
        atomicAdd(&cnt[rows[i] >> 8], 1);
    __syncthreads();
    loff[tid] = cnt[tid];
    __syncthreads();
#pragma unroll 1
    for (int off = 1; off < 256; off <<= 1) {
        int v = (tid >= off) ? loff[tid - off] : 0;
        __syncthreads();
        loff[tid] += v;
        __syncthreads();
    }
    int excl = loff[tid] - cnt[tid];
    __syncthreads();
    loff[tid] = excl;
    int gb = cnt[tid] ? atomicAdd(&gcur[tid], cnt[tid]) : 0;
    shiftv[tid] = gb - excl;
    __syncthreads();
#pragma unroll 1
    for (int i = i0 + tid; i < i1; i += 256) {
        int r = rows[i];
        int b = r >> 8;
        int s = loff[b] + atomicAdd(&cnt2[b], 1);
        sm_meta[s] = cols[i] | ((r & 255) << 16);
        sm_val[s]  = val[i];
        sm_bid[s]  = (unsigned char)b;
    }
    __syncthreads();
#pragma unroll 1
    for (int s = tid; s < m; s += 256) {
        int b = sm_bid[s];
        sdat[shiftv[b] + s] = make_int2(sm_meta[s], __float_as_int(sm_val[s]));
    }
}

// ------------- kb_sort: per-bucket LDS row-sort + per-row ptr ---------------
__global__ __launch_bounds__(256) void kb_sort(
    const int* __restrict__ bstart, int2* __restrict__ sdat,
    int* __restrict__ ptr, int2* __restrict__ scratch)
{
    __shared__ int cnt[256], off[256], cur[256];
    __shared__ int2 stage[SCAP];
    int tid = threadIdx.x;
    int b = blockIdx.x;
    int s = bstart[b], e = bstart[b + 1];
    int m = e - s;
    cnt[tid] = 0;
    __syncthreads();
    bool fits = (m <= SCAP);
    if (fits) {
#pragma unroll 1
        for (int i = tid; i < m; i += 256) {
            int2 d = sdat[s + i];
            stage[i] = d;
            atomicAdd(&cnt[(d.x >> 16) & 255], 1);
        }
    } else {
#pragma unroll 1
        for (int i = tid; i < m; i += 256) {
            int2 d = sdat[s + i];
            scratch[s + i] = d;
            atomicAdd(&cnt[(d.x >> 16) & 255], 1);
        }
    }
    __syncthreads();
    int c = cnt[tid];
    off[tid] = c;
    __syncthreads();
#pragma unroll 1
    for (int o = 1; o < 256; o <<= 1) {
        int v = (tid >= o) ? off[tid - o] : 0;
        __syncthreads();
        off[tid] += v;
        __syncthreads();
    }
    ptr[b * 256 + tid] = s + off[tid];
    cur[tid] = off[tid] - c;
    __syncthreads();
    if (fits) {
#pragma unroll 1
        for (int i = tid; i < m; i += 256) {
            int2 d = stage[i];
            int p = atomicAdd(&cur[(d.x >> 16) & 255], 1);
            sdat[s + p] = d;
        }
    } else {
        __threadfence();
        __syncthreads();
#pragma unroll 1
        for (int i = tid; i < m; i += 256) {
            int2 d = scratch[s + i];
            int p = atomicAdd(&cur[(d.x >> 16) & 255], 1);
            sdat[s + p] = d;
        }
    }
}

// ------------- gather spmm on packed sorted data (col in low 16 bits) -------
// unroll-8: issue 8 independent sdat loads, then 8 independent x-gathers --
// halves the serial {sdat -> x} latency batches per row vs unroll-4.
__global__ __launch_bounds__(256) void kb_gather(
    const int* __restrict__ ptr, const int2* __restrict__ sdat,
    const float* __restrict__ xin,
    float* __restrict__ out, int n)
{
    int r = blockIdx.x * 4 + (threadIdx.x >> 6);
    int lane = threadIdx.x & 63;
    if (r >= n) return;
    int s = (r == 0) ? 0 : ptr[r - 1];
    int e = ptr[r];
    float acc = 0.f;
    int k = s;
#pragma unroll 1
    for (; k + 7 < e; k += 8) {
        int2 d0 = sdat[k],     d1 = sdat[k + 1];
        int2 d2 = sdat[k + 2], d3 = sdat[k + 3];
        int2 d4 = sdat[k + 4], d5 = sdat[k + 5];
        int2 d6 = sdat[k + 6], d7 = sdat[k + 7];
        float x0 = xin[((d0.x & 0xFFFF) << 6) + lane];
        float x1 = xin[((d1.x & 0xFFFF) << 6) + lane];
        float x2 = xin[((d2.x & 0xFFFF) << 6) + lane];
        float x3 = xin[((d3.x & 0xFFFF) << 6) + lane];
        float x4 = xin[((d4.x & 0xFFFF) << 6) + lane];
        float x5 = xin[((d5.x & 0xFFFF) << 6) + lane];
        float x6 = xin[((d6.x & 0xFFFF) << 6) + lane];
        float x7 = xin[((d7.x & 0xFFFF) << 6) + lane];
        acc = fmaf(__int_as_float(d0.y), x0, acc);
        acc = fmaf(__int_as_float(d1.y), x1, acc);
        acc = fmaf(__int_as_float(d2.y), x2, acc);
        acc = fmaf(__int_as_float(d3.y), x3, acc);
        acc = fmaf(__int_as_float(d4.y), x4, acc);
        acc = fmaf(__int_as_float(d5.y), x5, acc);
        acc = fmaf(__int_as_float(d6.y), x6, acc);
        acc = fmaf(__int_as_float(d7.y), x7, acc);
    }
#pragma unroll 1
    for (; k + 1 < e; k += 2) {
        int2 d0 = sdat[k], d1 = sdat[k + 1];
        float x0 = xin[((d0.x & 0xFFFF) << 6) + lane];
        float x1 = xin[((d1.x & 0xFFFF) << 6) + lane];
        acc = fmaf(__int_as_float(d0.y), x0, acc);
        acc = fmaf(__int_as_float(d1.y), x1, acc);
    }
    if (k < e) {
        int2 d0 = sdat[k];
        acc = fmaf(__int_as_float(d0.y), xin[((d0.x & 0xFFFF) << 6) + lane], acc);
    }
    out[((size_t)r << 6) + lane] = acc;
}

// ---------------- tier-2 sequential CSR helpers (proven fallback) -----------
__global__ __launch_bounds__(256) void k_hist(
    const int* __restrict__ rows, int* __restrict__ cnt, int nnz)
{
    int i = blockIdx.x * 256 + threadIdx.x;
    int stride = gridDim.x * 256;
    for (; i < nnz; i += stride) atomicAdd(&cnt[rows[i]], 1);
}

__global__ __launch_bounds__(1024) void k_scan2(
    int* __restrict__ ptrK, int* __restrict__ ptrA)
{
    __shared__ int tot[1024];
    int* ptr = (blockIdx.x == 0) ? ptrK : ptrA;
    int t = threadIdx.x;
    int4* p4 = (int4*)(ptr + t * 64);
    int sum = 0;
#pragma unroll 1
    for (int q = 0; q < 16; ++q) {
        int4 b = p4[q];
        sum += b.x + b.y + b.z + b.w;
    }
    tot[t] = sum;
    __syncthreads();
#pragma unroll 1
    for (int off = 1; off < 1024; off <<= 1) {
        int v2 = 0;
        if (t >= off) v2 = tot[t - off];
        __syncthreads();
        if (t >= off) tot[t] += v2;
        __syncthreads();
    }
    int off = (t == 0) ? 0 : tot[t - 1];
#pragma unroll 1
    for (int q = 0; q < 16; ++q) {
        int4 b = p4[q];
        int4 w;
        w.x = off; off += b.x;
        w.y = off; off += b.y;
        w.z = off; off += b.z;
        w.w = off; off += b.w;
        p4[q] = w;
    }
}

__global__ __launch_bounds__(256) void k_scatter(
    const int* __restrict__ rows, const int* __restrict__ cols,
    const float* __restrict__ val, int* __restrict__ ptr,
    int2* __restrict__ sdat, int nnz)
{
    int i = blockIdx.x * 256 + threadIdx.x;
    int stride = gridDim.x * 256;
    for (; i < nnz; i += stride) {
        int p = atomicAdd(&ptr[rows[i]], 1);
        sdat[p] = make_int2(cols[i], __float_as_int(val[i]));
    }
}

__global__ __launch_bounds__(256) void k_gather(
    const int* __restrict__ ptr, const int2* __restrict__ sdat,
    const float* __restrict__ xin,
    float* __restrict__ out, int n)
{
    int r = blockIdx.x * 4 + (threadIdx.x >> 6);
    int lane = threadIdx.x & 63;
    if (r >= n) return;
    int s = (r == 0) ? 0 : ptr[r - 1];
    int e = ptr[r];
    float acc = 0.f;
    int k = s;
#pragma unroll 1
    for (; k + 3 < e; k += 4) {
        int2 d0 = sdat[k],     d1 = sdat[k + 1];
        int2 d2 = sdat[k + 2], d3 = sdat[k + 3];
        float x0 = xin[((size_t)d0.x << 6) + lane];
        float x1 = xin[((size_t)d1.x << 6) + lane];
        float x2 = xin[((size_t)d2.x << 6) + lane];
        float x3 = xin[((size_t)d3.x << 6) + lane];
        acc = fmaf(__int_as_float(d0.y), x0, acc);
        acc = fmaf(__int_as_float(d1.y), x1, acc);
        acc = fmaf(__int_as_float(d2.y), x2, acc);
        acc = fmaf(__int_as_float(d3.y), x3, acc);
    }
#pragma unroll 1
    for (; k < e; ++k) {
        int2 d0 = sdat[k];
        acc = fmaf(__int_as_float(d0.y), xin[((size_t)d0.x << 6) + lane], acc);
    }
    out[((size_t)r << 6) + lane] = acc;
}

// ---------------- tier-3 fallback spmm: COO scatter-atomic ------------------
__global__ __launch_bounds__(256) void k_spmm(
    const int* __restrict__ rows, const int* __restrict__ cols,
    const float* __restrict__ val, const float* __restrict__ xin,
    float* __restrict__ acc, int nnz)
{
    int wave = blockIdx.x * 4 + (threadIdx.x >> 6);
    int lane = threadIdx.x & 63;
    int e0 = wave * NZPW;
#pragma unroll 1
    for (int k = 0; k < NZPW; ++k) {
        int e = e0 + k;
        if (e >= nnz) break;
        int r = rows[e];
        int c = cols[e];
        float v = val[e];
        float xv = xin[((size_t)c << 6) + lane];
        unsafeAtomicAdd(&acc[((size_t)r << 6) + lane], v * xv);
    }
}

// ------- combine: recompute self-MLP, add spmm2 result, classifier dot ------
__global__ __launch_bounds__(256) void k_combine(
    const float* __restrict__ x,
    const float* __restrict__ W1, const float* __restrict__ b1,
    const float* __restrict__ W2, const float* __restrict__ b2,
    const float* __restrict__ Wc, const float* __restrict__ bcp,
    const float* __restrict__ x2b,
    float* __restrict__ out, float* __restrict__ x3, int n)
{
    int t = blockIdx.x * 256 + threadIdx.x;
    if (t >= n) return;
    const float* xr = x + (size_t)t * FI;

    float h[FO];
#pragma unroll
    for (int j = 0; j < FO; ++j) h[j] = b1[j];
#pragma unroll 1
    for (int ii = 0; ii < FI; ii += 4) {
        float4 xq = *(const float4*)(xr + ii);
#pragma unroll
        for (int j = 0; j < FO; ++j) h[j] = fmaf(xq.x, W1[(ii+0)*FO+j], h[j]);
#pragma unroll
        for (int j = 0; j < FO; ++j) h[j] = fmaf(xq.y, W1[(ii+1)*FO+j], h[j]);
#pragma unroll
        for (int j = 0; j < FO; ++j) h[j] = fmaf(xq.z, W1[(ii+2)*FO+j], h[j]);
#pragma unroll
        for (int j = 0; j < FO; ++j) h[j] = fmaf(xq.w, W1[(ii+3)*FO+j], h[j]);
    }
#pragma unroll
    for (int j = 0; j < FO; ++j) h[j] = fmaxf(h[j], 0.f);

    float o[FO];
#pragma unroll
    for (int j = 0; j < FO; ++j) o[j] = b2[j];
#pragma unroll 1
    for (int i = 0; i < FO; ++i) {
        float hi = h[i];
#pragma unroll
        for (int j = 0; j < FO; ++j) o[j] = fmaf(hi, W2[i*FO+j], o[j]);
    }

    const float4* q4 = (const float4*)(x2b + (size_t)t * FP);
    float4* dst = (float4*)(out + (size_t)t * FP);
    float dot = 0.f;
#pragma unroll
    for (int c = 0; c < 15; ++c) {
        float4 q = q4[c];
        float4 w;
        w.x = q.x + fmaxf(o[4*c+0], 0.f);
        w.y = q.y + fmaxf(o[4*c+1], 0.f);
        w.z = q.z + fmaxf(o[4*c+2], 0.f);
        w.w = q.w + fmaxf(o[4*c+3], 0.f);
        dot = fmaf(w.x, Wc[4*c+0], dot);
        dot = fmaf(w.y, Wc[4*c+1], dot);
        dot = fmaf(w.z, Wc[4*c+2], dot);
        dot = fmaf(w.w, Wc[4*c+3], dot);
        dst[c] = w;
    }
    {
        float4 q = q4[15];
        float4 w;
        w.x = q.x + fmaxf(o[60], 0.f);
        w.y = q.y + fmaxf(o[61], 0.f);
        w.z = q.z + fmaxf(o[62], 0.f);
        w.w = 0.f;
        dot = fmaf(w.x, Wc[60], dot);
        dot = fmaf(w.y, Wc[61], dot);
        dot = fmaf(w.z, Wc[62], dot);
        dst[15] = w;
    }
    x3[t] = dot + bcp[0];
}

// ---------------- sinkhorn v6 (best measured: 100 µs; reverted) -------------
#define SKP 332
__global__ __launch_bounds__(1024) __attribute__((amdgpu_waves_per_eu(4, 4)))
void k_sinkhorn(const float* __restrict__ x3, float* __restrict__ out)
{
    __shared__ float pm[32][SKP];
    __shared__ float ps[32][SKP];
    __shared__ float Rl[256];
    __shared__ float Cl[256];
    const int tid = threadIdx.x;
    const int ta = tid >> 5, tb = tid & 31;
    const int line4 = tid >> 2, sub = tid & 3;

    float u[8][8];
#pragma unroll
    for (int i = 0; i < 8; ++i) {
        const float4* src = (const float4*)(x3 + (ta*8 + i)*256 + tb*8);
        float4 a0 = src[0], a1 = src[1];
        const float sc = INV_TAU * LOG2E;
        u[i][0] = a0.x * sc; u[i][1] = a0.y * sc;
        u[i][2] = a0.z * sc; u[i][3] = a0.w * sc;
        u[i][4] = a1.x * sc; u[i][5] = a1.y * sc;
        u[i][6] = a1.z * sc; u[i][7] = a1.w * sc;
    }
    if (tid < 256) { Rl[tid] = 0.f; Cl[tid] = 0.f; }
    __syncthreads();

    // ---- iters 0,1: max-tracked ----
#pragma unroll 1
    for (int it = 0; it < 2; ++it) {
        const bool even = (it & 1) == 0;
        float sm[8], ss[8];
        if (even) {
            float r[8];
#pragma unroll
            for (int i = 0; i < 8; ++i) r[i] = Rl[ta*8 + i];
#pragma unroll
            for (int j = 0; j < 8; ++j) {
                float m = u[0][j] - r[0];
#pragma unroll
                for (int i = 1; i < 8; ++i) m = fmaxf(m, u[i][j] - r[i]);
                float s0 = 0.f, s1 = 0.f;
#pragma unroll
                for (int i = 0; i < 8; i += 2) {
                    s0 += fexp2(u[i][j] - r[i] - m);
                    s1 += fexp2(u[i+1][j] - r[i+1] - m);
                }
                sm[j] = m; ss[j] = s0 + s1;
            }
        } else {
            float c[8];
#pragma unroll
            for (int j = 0; j < 8; ++j) c[j] = Cl[tb*8 + j];
#pragma unroll
            for (int i = 0; i < 8; ++i) {
                float m = u[i][0] - c[0];
#pragma unroll
                for (int j = 1; j < 8; ++j) m = fmaxf(m, u[i][j] - c[j]);
                float s0 = 0.f, s1 = 0.f;
#pragma unroll
                for (int j = 0; j < 8; j += 2) {
                    s0 += fexp2(u[i][j] - c[j] - m);
                    s1 += fexp2(u[i][j+1] - c[j+1] - m);
                }
                sm[i] = m; ss[i] = s0 + s1;
            }
        }
        {
            float* mrow = even ? &pm[ta][tb*8] : &pm[tb][ta*8];
            float* srow = even ? &ps[ta][tb*8] : &ps[tb][ta*8];
            ((float4*)mrow)[0] = make_float4(sm[0], sm[1], sm[2], sm[3]);
            ((float4*)mrow)[1] = make_float4(sm[4], sm[5], sm[6], sm[7]);
            ((float4*)srow)[0] = make_float4(ss[0], ss[1], ss[2], ss[3]);
            ((float4*)srow)[1] = make_float4(ss[4], ss[5], ss[6], ss[7]);
        }
        __syncthreads();
        float M = pm[sub*8][line4];
        float S = ps[sub*8][line4];
#pragma unroll
        for (int k = 1; k < 8; ++k) {
            float m2 = pm[sub*8 + k][line4];
            float s2 = ps[sub*8 + k][line4];
            float nm = fmaxf(M, m2);
            S = S * fexp2(M - nm) + s2 * fexp2(m2 - nm);
            M = nm;
        }
#pragma unroll
        for (int d = 1; d <= 2; d <<= 1) {
            float m2 = __shfl_xor(M, d);
            float s2 = __shfl_xor(S, d);
            float nm = fmaxf(M, m2);
            S = S * fexp2(M - nm) + s2 * fexp2(m2 - nm);
            M = nm;
        }
        if (sub == 0) {
            float l = M + flog2(S);
            if (even) Cl[line4] = l; else Rl[line4] = l;
        }
        __syncthreads();
    }

    // ---- iters 2..19: previous-offset shift, single pass, sum-only merge ---
#pragma unroll 1
    for (int it = 2; it < 20; ++it) {
        const bool even = (it & 1) == 0;
        float r[8], c[8], ss[8];
#pragma unroll
        for (int i = 0; i < 8; ++i) r[i] = Rl[ta*8 + i];
#pragma unroll
        for (int j = 0; j < 8; ++j) c[j] = Cl[tb*8 + j];
        if (even) {
#pragma unroll
            for (int j = 0; j < 8; ++j) {
                float s0 = 0.f, s1 = 0.f;
#pragma unroll
                for (int i = 0; i < 8; i += 2) {
                    s0 += fexp2(u[i][j] - r[i] - c[j]);
                    s1 += fexp2(u[i+1][j] - r[i+1] - c[j]);
                }
                ss[j] = s0 + s1;
            }
        } else {
#pragma unroll
            for (int i = 0; i < 8; ++i) {
                float s0 = 0.f, s1 = 0.f;
#pragma unroll
                for (int j = 0; j < 8; j += 2) {
                    s0 += fexp2(u[i][j] - c[j] - r[i]);
                    s1 += fexp2(u[i][j+1] - c[j+1] - r[i]);
                }
                ss[i] = s0 + s1;
            }
        }
        {
            float* srow = even ? &ps[ta][tb*8] : &ps[tb][ta*8];
            ((float4*)srow)[0] = make_float4(ss[0], ss[1], ss[2], ss[3]);
            ((float4*)srow)[1] = make_float4(ss[4], ss[5], ss[6], ss[7]);
        }
        __syncthreads();
        float S = 0.f;
#pragma unroll
        for (int k = 0; k < 8; ++k) S += ps[sub*8 + k][line4];
        S += __shfl_xor(S, 1);
        S += __shfl_xor(S, 2);
        if (sub == 0) {
            float d = flog2(S);
            if (even) Cl[line4] += d; else Rl[line4] += d;
        }
        __syncthreads();
    }

    float r[8], c[8];
#pragma unroll
    for (int i = 0; i < 8; ++i) r[i] = Rl[ta*8 + i];
#pragma unroll
    for (int j = 0; j < 8; ++j) c[j] = Cl[tb*8 + j];
#pragma unroll
    for (int i = 0; i < 8; ++i) {
        int a = ta*8 + i;
#pragma unroll
        for (int j = 0; j < 8; ++j) {
            out[((size_t)(a*256 + tb*8 + j) << 6) + 63] =
                fexp2(u[i][j] - r[i] - c[j]);
        }
    }
}

extern "C" void kernel_launch(void* const* d_in, const int* in_sizes, int n_in,
                              void* d_out, int out_size, void* d_ws, size_t ws_size,
                              hipStream_t stream)
{
    const float* K_value = (const float*)d_in[0];
    const int*   K_index = (const int*)d_in[1];
    const float* A_value = (const float*)d_in[2];
    const int*   A_index = (const int*)d_in[3];
    const float* x   = (const float*)d_in[4];
    const float* Wn1 = (const float*)d_in[5];
    const float* bn1 = (const float*)d_in[6];
    const float* Wn2 = (const float*)d_in[7];
    const float* bn2 = (const float*)d_in[8];
    const float* Ws1 = (const float*)d_in[9];
    const float* bs1 = (const float*)d_in[10];
    const float* Ws2 = (const float*)d_in[11];
    const float* bs2 = (const float*)d_in[12];
    const float* Wc  = (const float*)d_in[13];
    const float* bc  = (const float*)d_in[14];

    int nnzK = in_sizes[0];
    int nnzA = in_sizes[2];
    int n    = in_sizes[4] / FI;   // 65536

    const int* rowsK = K_index;  const int* colsK = K_index + nnzK;
    const int* rowsA = A_index;  const int* colsA = A_index + nnzA;

    float* outf = (float*)d_out;
    char*  ws   = (char*)d_ws;
    float* bufA = (float*)ws;                         // 16MB: x1, later x2
    float* x3   = bufA + (size_t)n * FP;              // n floats (tables aliased
    int*   tbl  = (int*)x3;                           //  during build phase)
    int*   cntK = tbl;          int* cntA = tbl + 256;
    int*   bstK = tbl + 512;    int* gcrK = tbl + 772;
    int*   bstA = tbl + 1032;   int* gcrA = tbl + 1292;
    int*   ptrKf = (int*)(x3 + n);                    // n ints
    int*   ptrAf = ptrKf + n;                         // n ints
    int2*  sdatK = (int2*)(ptrAf + n);                // nnzK entries
    int2*  sdatA = sdatK + nnzK;                      // nnzA entries

    size_t need1 = ((size_t)n * FP + 3 * (size_t)n) * 4 + ((size_t)nnzK + nnzA) * 8;
    size_t need2 = ((size_t)n * FP + 2 * (size_t)n) * 4 + (size_t)nnzK * 8;

    // 1. n_func MLP -> bufA (x1, padded to 64)
    k_mlp_n<<<(n + 255) / 256, 256, 0, stream>>>(x, Wn1, bn1, Wn2, bn2, bufA, n);

    if (ws_size >= need1 && n == 65536 && nnzK <= (1 << 24) && nnzA <= (1 << 24)) {
        // ---- tier 1: bucket + LDS row-sort + high-TLP gather ----
        (void)hipMemsetAsync(cntK, 0, 512 * 4, stream);
        k_hist256<<<512, 256, 0, stream>>>(rowsK, rowsA, cntK, cntA, nnzK, nnzA);
        k_scan256<<<1, 256, 0, stream>>>(cntK, cntA, bstK, gcrK, bstA, gcrA);
        kb_bucket<<<(nnzK + CHUNK - 1) / CHUNK, 256, 0, stream>>>(
            rowsK, colsK, K_value, gcrK, sdatK, nnzK);
        kb_bucket<<<(nnzA + CHUNK - 1) / CHUNK, 256, 0, stream>>>(
            rowsA, colsA, A_value, gcrA, sdatA, nnzA);
        kb_sort<<<256, 256, 0, stream>>>(bstK, sdatK, ptrKf, (int2*)outf);
        kb_sort<<<256, 256, 0, stream>>>(bstA, sdatA, ptrAf, (int2*)outf);
        // Wx(d_out) = K @ x1 ; x2(bufA) = A @ Wx
        kb_gather<<<(n + 3) / 4, 256, 0, stream>>>(ptrKf, sdatK, bufA, outf, n);
        kb_gather<<<(n + 3) / 4, 256, 0, stream>>>(ptrAf, sdatA, outf, bufA, n);
    } else if (ws_size >= need2 && n == 65536) {
        // ---- tier 2: sequential CSR (proven) ----
        int* ptrK = (int*)(x3 + n);
        int2* sdat2 = (int2*)(ptrK + n);
        (void)hipMemsetAsync(ptrK, 0, (size_t)n * 4, stream);
        k_hist<<<2048, 256, 0, stream>>>(rowsK, ptrK, nnzK);
        k_scan2<<<1, 1024, 0, stream>>>(ptrK, ptrK);
        k_scatter<<<2048, 256, 0, stream>>>(rowsK, colsK, K_value, ptrK, sdat2, nnzK);
        k_gather<<<(n + 3) / 4, 256, 0, stream>>>(ptrK, sdat2, bufA, outf, n);
        (void)hipMemsetAsync(ptrK, 0, (size_t)n * 4, stream);
        k_hist<<<2048, 256, 0, stream>>>(rowsA, ptrK, nnzA);
        k_scan2<<<1, 1024, 0, stream>>>(ptrK, ptrK);
        k_scatter<<<2048, 256, 0, stream>>>(rowsA, colsA, A_value, ptrK, sdat2, nnzA);
        k_gather<<<(n + 3) / 4, 256, 0, stream>>>(ptrK, sdat2, outf, bufA, n);
    } else {
        // ---- tier 3: atomic scatter fallback ----
        (void)hipMemsetAsync(outf, 0, (size_t)n * FP * 4, stream);
        int blocks1 = (nnzK + 4 * NZPW - 1) / (4 * NZPW);
        k_spmm<<<blocks1, 256, 0, stream>>>(rowsK, colsK, K_value, bufA, outf, nnzK);
        (void)hipMemsetAsync(bufA, 0, (size_t)n * FP * 4, stream);
        int blocks2 = (nnzA + 4 * NZPW - 1) / (4 * NZPW);
        k_spmm<<<blocks2, 256, 0, stream>>>(rowsA, colsA, A_value, outf, bufA, nnzA);
    }

    // combine: self-MLP + x2(bufA), write out[:, :63], classifier -> x3
    k_combine<<<(n + 255) / 256, 256, 0, stream>>>(x, Ws1, bs1, Ws2, bs2, Wc, bc,
                                                   bufA, outf, x3, n);
    // sinkhorn -> out[:, 63]
    k_sinkhorn<<<1, 1024, 0, stream>>>(x3, outf);
}

// Round 14
// 357.284 us; speedup vs baseline: 1.1267x; 1.0568x over previous
//
#include <hip/hip_runtime.h>
#include <hip/hip_bf16.h>

#define FI 64
#define FO 63
#define FP 64
#define NZPW 8
#define INV_TAU 20.0f
#define LOG2E 1.4426950408889634f
#define CHUNK 4096
#define SCAP 12288   // kb_sort LDS staging capacity (96KB)

// raw gfx950 transcendentals: v_exp_f32 = 2^x, v_log_f32 = log2(x).
__device__ __forceinline__ float fexp2(float x) {
    float y; asm("v_exp_f32 %0, %1" : "=v"(y) : "v"(x)); return y;
}
__device__ __forceinline__ float flog2(float x) {
    float y; asm("v_log_f32 %0, %1" : "=v"(y) : "v"(x)); return y;
}

// ---------------- device body: n_func MLP for one node row ------------------
__device__ __forceinline__ void mlp_body(
    const float* __restrict__ x,
    const float* __restrict__ W1, const float* __restrict__ b1,
    const float* __restrict__ W2, const float* __restrict__ b2,
    float* __restrict__ x1p, int t)
{
    const float* xr = x + (size_t)t * FI;
    float h[FO];
#pragma unroll
    for (int j = 0; j < FO; ++j) h[j] = b1[j];
#pragma unroll 1
    for (int ii = 0; ii < FI; ii += 4) {
        float4 xq = *(const float4*)(xr + ii);
#pragma unroll
        for (int j = 0; j < FO; ++j) h[j] = fmaf(xq.x, W1[(ii+0)*FO+j], h[j]);
#pragma unroll
        for (int j = 0; j < FO; ++j) h[j] = fmaf(xq.y, W1[(ii+1)*FO+j], h[j]);
#pragma unroll
        for (int j = 0; j < FO; ++j) h[j] = fmaf(xq.z, W1[(ii+2)*FO+j], h[j]);
#pragma unroll
        for (int j = 0; j < FO; ++j) h[j] = fmaf(xq.w, W1[(ii+3)*FO+j], h[j]);
    }
#pragma unroll
    for (int j = 0; j < FO; ++j) h[j] = fmaxf(h[j], 0.f);

    float o[FO];
#pragma unroll
    for (int j = 0; j < FO; ++j) o[j] = b2[j];
#pragma unroll 1
    for (int i = 0; i < FO; ++i) {
        float hi = h[i];
#pragma unroll
        for (int j = 0; j < FO; ++j) o[j] = fmaf(hi, W2[i*FO+j], o[j]);
    }

    float* dst = x1p + (size_t)t * FP;
#pragma unroll
    for (int c = 0; c < 15; ++c) {
        float4 w;
        w.x = fmaxf(o[4*c+0], 0.f);
        w.y = fmaxf(o[4*c+1], 0.f);
        w.z = fmaxf(o[4*c+2], 0.f);
        w.w = fmaxf(o[4*c+3], 0.f);
        ((float4*)dst)[c] = w;
    }
    {
        float4 w;
        w.x = fmaxf(o[60], 0.f);
        w.y = fmaxf(o[61], 0.f);
        w.z = fmaxf(o[62], 0.f);
        w.w = 0.f;
        ((float4*)dst)[15] = w;
    }
}

// -------- fused: blocks [0,nbM) run MLP; blocks [nbM, nbM+512) run hist -----
// MLP is VALU-heavy, hist is memory/atomic-heavy: complementary co-residency.
__global__ __launch_bounds__(256) void k_mlp_hist(
    const float* __restrict__ x,
    const float* __restrict__ W1, const float* __restrict__ b1,
    const float* __restrict__ W2, const float* __restrict__ b2,
    float* __restrict__ x1p, int n,
    const int* __restrict__ rowsK, const int* __restrict__ rowsA,
    int* __restrict__ cntK, int* __restrict__ cntA, int nnzK, int nnzA)
{
    int nbM = n >> 8;
    int tid = threadIdx.x;
    if ((int)blockIdx.x < nbM) {
        int t = blockIdx.x * 256 + tid;
        if (t < n) mlp_body(x, W1, b1, W2, b2, x1p, t);
    } else {
        __shared__ int h[512];
        h[tid] = 0; h[tid + 256] = 0;
        __syncthreads();
        int nbH = gridDim.x - nbM;
        int i = ((int)blockIdx.x - nbM) * 256 + tid;
        int stride = nbH * 256;
        int total = nnzK + nnzA;
        for (; i < total; i += stride) {
            if (i < nnzK) atomicAdd(&h[rowsK[i] >> 8], 1);
            else          atomicAdd(&h[256 + (rowsA[i - nnzK] >> 8)], 1);
        }
        __syncthreads();
        if (h[tid])       atomicAdd(&cntK[tid], h[tid]);
        if (h[tid + 256]) atomicAdd(&cntA[tid], h[tid + 256]);
    }
}

// ------------- scan 256 counts -> bstart[257] and gcur cursors (1 block) ----
__global__ __launch_bounds__(256) void k_scan256(
    const int* __restrict__ cntK, const int* __restrict__ cntA,
    int* __restrict__ bstartK, int* __restrict__ gcurK,
    int* __restrict__ bstartA, int* __restrict__ gcurA)
{
    __shared__ int tmp[256];
    int t = threadIdx.x;
    int c = cntK[t];
    tmp[t] = c; __syncthreads();
#pragma unroll 1
    for (int off = 1; off < 256; off <<= 1) {
        int v = (t >= off) ? tmp[t - off] : 0;
        __syncthreads();
        tmp[t] += v;
        __syncthreads();
    }
    bstartK[t + 1] = tmp[t];
    gcurK[t] = tmp[t] - c;
    if (t == 0) bstartK[0] = 0;
    __syncthreads();
    c = cntA[t];
    tmp[t] = c; __syncthreads();
#pragma unroll 1
    for (int off = 1; off < 256; off <<= 1) {
        int v = (t >= off) ? tmp[t - off] : 0;
        __syncthreads();
        tmp[t] += v;
        __syncthreads();
    }
    bstartA[t + 1] = tmp[t];
    gcurA[t] = tmp[t] - c;
    if (t == 0) bstartA[0] = 0;
}

// ------------- merged bucket pass for K (blocks < nbK) and A ----------------
__global__ __launch_bounds__(256) void kb_bucket2(
    const int* __restrict__ rowsK, const int* __restrict__ colsK,
    const float* __restrict__ valK, int* __restrict__ gcurK,
    int2* __restrict__ sdatK, int nnzK, int nbK,
    const int* __restrict__ rowsA, const int* __restrict__ colsA,
    const float* __restrict__ valA, int* __restrict__ gcurA,
    int2* __restrict__ sdatA, int nnzA)
{
    __shared__ int cnt[256], loff[256], cnt2[256], shiftv[256];
    __shared__ int sm_meta[CHUNK];
    __shared__ float sm_val[CHUNK];
    __shared__ unsigned char sm_bid[CHUNK];
    const int* rows; const int* cols; const float* val;
    int* gcur; int2* sdat; int nnz, i0;
    if ((int)blockIdx.x < nbK) {
        rows = rowsK; cols = colsK; val = valK; gcur = gcurK; sdat = sdatK;
        nnz = nnzK; i0 = blockIdx.x * CHUNK;
    } else {
        rows = rowsA; cols = colsA; val = valA; gcur = gcurA; sdat = sdatA;
        nnz = nnzA; i0 = ((int)blockIdx.x - nbK) * CHUNK;
    }
    int tid = threadIdx.x;
    int i1 = min(i0 + CHUNK, nnz);
    int m = i1 - i0;

    cnt[tid] = 0; cnt2[tid] = 0;
    __syncthreads();
#pragma unroll 1
    for (int i = i0 + tid; i < i1; i += 256)
        atomicAdd(&cnt[rows[i] >> 8], 1);
    __syncthreads();
    loff[tid] = cnt[tid];
    __syncthreads();
#pragma unroll 1
    for (int off = 1; off < 256; off <<= 1) {
        int v = (tid >= off) ? loff[tid - off] : 0;
        __syncthreads();
        loff[tid] += v;
        __syncthreads();
    }
    int excl = loff[tid] - cnt[tid];
    __syncthreads();
    loff[tid] = excl;
    int gb = cnt[tid] ? atomicAdd(&gcur[tid], cnt[tid]) : 0;
    shiftv[tid] = gb - excl;
    __syncthreads();
#pragma unroll 1
    for (int i = i0 + tid; i < i1; i += 256) {
        int r = rows[i];
        int b = r >> 8;
        int s = loff[b] + atomicAdd(&cnt2[b], 1);
        sm_meta[s] = cols[i] | ((r & 255) << 16);
        sm_val[s]  = val[i];
        sm_bid[s]  = (unsigned char)b;
    }
    __syncthreads();
#pragma unroll 1
    for (int s = tid; s < m; s += 256) {
        int b = sm_bid[s];
        sdat[shiftv[b] + s] = make_int2(sm_meta[s], __float_as_int(sm_val[s]));
    }
}

// ------------- merged per-bucket LDS row-sort: K (blocks<256) and A ---------
__global__ __launch_bounds__(256) void kb_sort2(
    const int* __restrict__ bstK, int2* __restrict__ sdatK,
    int* __restrict__ ptrK, int2* __restrict__ scrK,
    const int* __restrict__ bstA, int2* __restrict__ sdatA,
    int* __restrict__ ptrA, int2* __restrict__ scrA)
{
    __shared__ int cnt[256], off[256], cur[256];
    __shared__ int2 stage[SCAP];
    const int* bstart; int2* sdat; int* ptr; int2* scratch; int b;
    if (blockIdx.x < 256) {
        b = blockIdx.x; bstart = bstK; sdat = sdatK; ptr = ptrK; scratch = scrK;
    } else {
        b = blockIdx.x - 256; bstart = bstA; sdat = sdatA; ptr = ptrA; scratch = scrA;
    }
    int tid = threadIdx.x;
    int s = bstart[b], e = bstart[b + 1];
    int m = e - s;
    cnt[tid] = 0;
    __syncthreads();
    bool fits = (m <= SCAP);
    if (fits) {
#pragma unroll 1
        for (int i = tid; i < m; i += 256) {
            int2 d = sdat[s + i];
            stage[i] = d;
            atomicAdd(&cnt[(d.x >> 16) & 255], 1);
        }
    } else {
#pragma unroll 1
        for (int i = tid; i < m; i += 256) {
            int2 d = sdat[s + i];
            scratch[s + i] = d;
            atomicAdd(&cnt[(d.x >> 16) & 255], 1);
        }
    }
    __syncthreads();
    int c = cnt[tid];
    off[tid] = c;
    __syncthreads();
#pragma unroll 1
    for (int o = 1; o < 256; o <<= 1) {
        int v = (tid >= o) ? off[tid - o] : 0;
        __syncthreads();
        off[tid] += v;
        __syncthreads();
    }
    ptr[b * 256 + tid] = s + off[tid];
    cur[tid] = off[tid] - c;
    __syncthreads();
    if (fits) {
#pragma unroll 1
        for (int i = tid; i < m; i += 256) {
            int2 d = stage[i];
            int p = atomicAdd(&cur[(d.x >> 16) & 255], 1);
            sdat[s + p] = d;
        }
    } else {
        __threadfence();
        __syncthreads();
#pragma unroll 1
        for (int i = tid; i < m; i += 256) {
            int2 d = scratch[s + i];
            int p = atomicAdd(&cur[(d.x >> 16) & 255], 1);
            sdat[s + p] = d;
        }
    }
}

// ------------- gather spmm on packed sorted data (col in low 16 bits) -------
// unroll-8: 8 independent sdat loads then 8 independent x-gathers in flight.
__global__ __launch_bounds__(256) void kb_gather(
    const int* __restrict__ ptr, const int2* __restrict__ sdat,
    const float* __restrict__ xin,
    float* __restrict__ out, int n)
{
    int r = blockIdx.x * 4 + (threadIdx.x >> 6);
    int lane = threadIdx.x & 63;
    if (r >= n) return;
    int s = (r == 0) ? 0 : ptr[r - 1];
    int e = ptr[r];
    float acc = 0.f;
    int k = s;
#pragma unroll 1
    for (; k + 7 < e; k += 8) {
        int2 d0 = sdat[k],     d1 = sdat[k + 1];
        int2 d2 = sdat[k + 2], d3 = sdat[k + 3];
        int2 d4 = sdat[k + 4], d5 = sdat[k + 5];
        int2 d6 = sdat[k + 6], d7 = sdat[k + 7];
        float x0 = xin[((d0.x & 0xFFFF) << 6) + lane];
        float x1 = xin[((d1.x & 0xFFFF) << 6) + lane];
        float x2 = xin[((d2.x & 0xFFFF) << 6) + lane];
        float x3 = xin[((d3.x & 0xFFFF) << 6) + lane];
        float x4 = xin[((d4.x & 0xFFFF) << 6) + lane];
        float x5 = xin[((d5.x & 0xFFFF) << 6) + lane];
        float x6 = xin[((d6.x & 0xFFFF) << 6) + lane];
        float x7 = xin[((d7.x & 0xFFFF) << 6) + lane];
        acc = fmaf(__int_as_float(d0.y), x0, acc);
        acc = fmaf(__int_as_float(d1.y), x1, acc);
        acc = fmaf(__int_as_float(d2.y), x2, acc);
        acc = fmaf(__int_as_float(d3.y), x3, acc);
        acc = fmaf(__int_as_float(d4.y), x4, acc);
        acc = fmaf(__int_as_float(d5.y), x5, acc);
        acc = fmaf(__int_as_float(d6.y), x6, acc);
        acc = fmaf(__int_as_float(d7.y), x7, acc);
    }
#pragma unroll 1
    for (; k + 1 < e; k += 2) {
        int2 d0 = sdat[k], d1 = sdat[k + 1];
        float x0 = xin[((d0.x & 0xFFFF) << 6) + lane];
        float x1 = xin[((d1.x & 0xFFFF) << 6) + lane];
        acc = fmaf(__int_as_float(d0.y), x0, acc);
        acc = fmaf(__int_as_float(d1.y), x1, acc);
    }
    if (k < e) {
        int2 d0 = sdat[k];
        acc = fmaf(__int_as_float(d0.y), xin[((d0.x & 0xFFFF) << 6) + lane], acc);
    }
    out[((size_t)r << 6) + lane] = acc;
}

// ---------------- tier-2 sequential CSR helpers (proven fallback) -----------
__global__ __launch_bounds__(256) void k_mlp_n(
    const float* __restrict__ x,
    const float* __restrict__ W1, const float* __restrict__ b1,
    const float* __restrict__ W2, const float* __restrict__ b2,
    float* __restrict__ x1p, int n)
{
    int t = blockIdx.x * 256 + threadIdx.x;
    if (t < n) mlp_body(x, W1, b1, W2, b2, x1p, t);
}

__global__ __launch_bounds__(256) void k_hist(
    const int* __restrict__ rows, int* __restrict__ cnt, int nnz)
{
    int i = blockIdx.x * 256 + threadIdx.x;
    int stride = gridDim.x * 256;
    for (; i < nnz; i += stride) atomicAdd(&cnt[rows[i]], 1);
}

__global__ __launch_bounds__(1024) void k_scan2(
    int* __restrict__ ptrK, int* __restrict__ ptrA)
{
    __shared__ int tot[1024];
    int* ptr = (blockIdx.x == 0) ? ptrK : ptrA;
    int t = threadIdx.x;
    int4* p4 = (int4*)(ptr + t * 64);
    int sum = 0;
#pragma unroll 1
    for (int q = 0; q < 16; ++q) {
        int4 b = p4[q];
        sum += b.x + b.y + b.z + b.w;
    }
    tot[t] = sum;
    __syncthreads();
#pragma unroll 1
    for (int off = 1; off < 1024; off <<= 1) {
        int v2 = 0;
        if (t >= off) v2 = tot[t - off];
        __syncthreads();
        if (t >= off) tot[t] += v2;
        __syncthreads();
    }
    int off = (t == 0) ? 0 : tot[t - 1];
#pragma unroll 1
    for (int q = 0; q < 16; ++q) {
        int4 b = p4[q];
        int4 w;
        w.x = off; off += b.x;
        w.y = off; off += b.y;
        w.z = off; off += b.z;
        w.w = off; off += b.w;
        p4[q] = w;
    }
}

__global__ __launch_bounds__(256) void k_scatter(
    const int* __restrict__ rows, const int* __restrict__ cols,
    const float* __restrict__ val, int* __restrict__ ptr,
    int2* __restrict__ sdat, int nnz)
{
    int i = blockIdx.x * 256 + threadIdx.x;
    int stride = gridDim.x * 256;
    for (; i < nnz; i += stride) {
        int p = atomicAdd(&ptr[rows[i]], 1);
        sdat[p] = make_int2(cols[i], __float_as_int(val[i]));
    }
}

__global__ __launch_bounds__(256) void k_gather(
    const int* __restrict__ ptr, const int2* __restrict__ sdat,
    const float* __restrict__ xin,
    float* __restrict__ out, int n)
{
    int r = blockIdx.x * 4 + (threadIdx.x >> 6);
    int lane = threadIdx.x & 63;
    if (r >= n) return;
    int s = (r == 0) ? 0 : ptr[r - 1];
    int e = ptr[r];
    float acc = 0.f;
    int k = s;
#pragma unroll 1
    for (; k + 3 < e; k += 4) {
        int2 d0 = sdat[k],     d1 = sdat[k + 1];
        int2 d2 = sdat[k + 2], d3 = sdat[k + 3];
        float x0 = xin[((size_t)d0.x << 6) + lane];
        float x1 = xin[((size_t)d1.x << 6) + lane];
        float x2 = xin[((size_t)d2.x << 6) + lane];
        float x3 = xin[((size_t)d3.x << 6) + lane];
        acc = fmaf(__int_as_float(d0.y), x0, acc);
        acc = fmaf(__int_as_float(d1.y), x1, acc);
        acc = fmaf(__int_as_float(d2.y), x2, acc);
        acc = fmaf(__int_as_float(d3.y), x3, acc);
    }
#pragma unroll 1
    for (; k < e; ++k) {
        int2 d0 = sdat[k];
        acc = fmaf(__int_as_float(d0.y), xin[((size_t)d0.x << 6) + lane], acc);
    }
    out[((size_t)r << 6) + lane] = acc;
}

// ---------------- tier-3 fallback spmm: COO scatter-atomic ------------------
__global__ __launch_bounds__(256) void k_spmm(
    const int* __restrict__ rows, const int* __restrict__ cols,
    const float* __restrict__ val, const float* __restrict__ xin,
    float* __restrict__ acc, int nnz)
{
    int wave = blockIdx.x * 4 + (threadIdx.x >> 6);
    int lane = threadIdx.x & 63;
    int e0 = wave * NZPW;
#pragma unroll 1
    for (int k = 0; k < NZPW; ++k) {
        int e = e0 + k;
        if (e >= nnz) break;
        int r = rows[e];
        int c = cols[e];
        float v = val[e];
        float xv = xin[((size_t)c << 6) + lane];
        unsafeAtomicAdd(&acc[((size_t)r << 6) + lane], v * xv);
    }
}

// ------- combine: recompute self-MLP, add spmm2 result, classifier dot ------
__global__ __launch_bounds__(256) void k_combine(
    const float* __restrict__ x,
    const float* __restrict__ W1, const float* __restrict__ b1,
    const float* __restrict__ W2, const float* __restrict__ b2,
    const float* __restrict__ Wc, const float* __restrict__ bcp,
    const float* __restrict__ x2b,
    float* __restrict__ out, float* __restrict__ x3, int n)
{
    int t = blockIdx.x * 256 + threadIdx.x;
    if (t >= n) return;
    const float* xr = x + (size_t)t * FI;

    float h[FO];
#pragma unroll
    for (int j = 0; j < FO; ++j) h[j] = b1[j];
#pragma unroll 1
    for (int ii = 0; ii < FI; ii += 4) {
        float4 xq = *(const float4*)(xr + ii);
#pragma unroll
        for (int j = 0; j < FO; ++j) h[j] = fmaf(xq.x, W1[(ii+0)*FO+j], h[j]);
#pragma unroll
        for (int j = 0; j < FO; ++j) h[j] = fmaf(xq.y, W1[(ii+1)*FO+j], h[j]);
#pragma unroll
        for (int j = 0; j < FO; ++j) h[j] = fmaf(xq.z, W1[(ii+2)*FO+j], h[j]);
#pragma unroll
        for (int j = 0; j < FO; ++j) h[j] = fmaf(xq.w, W1[(ii+3)*FO+j], h[j]);
    }
#pragma unroll
    for (int j = 0; j < FO; ++j) h[j] = fmaxf(h[j], 0.f);

    float o[FO];
#pragma unroll
    for (int j = 0; j < FO; ++j) o[j] = b2[j];
#pragma unroll 1
    for (int i = 0; i < FO; ++i) {
        float hi = h[i];
#pragma unroll
        for (int j = 0; j < FO; ++j) o[j] = fmaf(hi, W2[i*FO+j], o[j]);
    }

    const float4* q4 = (const float4*)(x2b + (size_t)t * FP);
    float4* dst = (float4*)(out + (size_t)t * FP);
    float dot = 0.f;
#pragma unroll
    for (int c = 0; c < 15; ++c) {
        float4 q = q4[c];
        float4 w;
        w.x = q.x + fmaxf(o[4*c+0], 0.f);
        w.y = q.y + fmaxf(o[4*c+1], 0.f);
        w.z = q.z + fmaxf(o[4*c+2], 0.f);
        w.w = q.w + fmaxf(o[4*c+3], 0.f);
        dot = fmaf(w.x, Wc[4*c+0], dot);
        dot = fmaf(w.y, Wc[4*c+1], dot);
        dot = fmaf(w.z, Wc[4*c+2], dot);
        dot = fmaf(w.w, Wc[4*c+3], dot);
        dst[c] = w;
    }
    {
        float4 q = q4[15];
        float4 w;
        w.x = q.x + fmaxf(o[60], 0.f);
        w.y = q.y + fmaxf(o[61], 0.f);
        w.z = q.z + fmaxf(o[62], 0.f);
        w.w = 0.f;
        dot = fmaf(w.x, Wc[60], dot);
        dot = fmaf(w.y, Wc[61], dot);
        dot = fmaf(w.z, Wc[62], dot);
        dst[15] = w;
    }
    x3[t] = dot + bcp[0];
}

// ---------------- sinkhorn v6 (best measured: 100 µs) -----------------------
#define SKP 332
__global__ __launch_bounds__(1024) __attribute__((amdgpu_waves_per_eu(4, 4)))
void k_sinkhorn(const float* __restrict__ x3, float* __restrict__ out)
{
    __shared__ float pm[32][SKP];
    __shared__ float ps[32][SKP];
    __shared__ float Rl[256];
    __shared__ float Cl[256];
    const int tid = threadIdx.x;
    const int ta = tid >> 5, tb = tid & 31;
    const int line4 = tid >> 2, sub = tid & 3;

    float u[8][8];
#pragma unroll
    for (int i = 0; i < 8; ++i) {
        const float4* src = (const float4*)(x3 + (ta*8 + i)*256 + tb*8);
        float4 a0 = src[0], a1 = src[1];
        const float sc = INV_TAU * LOG2E;
        u[i][0] = a0.x * sc; u[i][1] = a0.y * sc;
        u[i][2] = a0.z * sc; u[i][3] = a0.w * sc;
        u[i][4] = a1.x * sc; u[i][5] = a1.y * sc;
        u[i][6] = a1.z * sc; u[i][7] = a1.w * sc;
    }
    if (tid < 256) { Rl[tid] = 0.f; Cl[tid] = 0.f; }
    __syncthreads();

    // ---- iters 0,1: max-tracked ----
#pragma unroll 1
    for (int it = 0; it < 2; ++it) {
        const bool even = (it & 1) == 0;
        float sm[8], ss[8];
        if (even) {
            float r[8];
#pragma unroll
            for (int i = 0; i < 8; ++i) r[i] = Rl[ta*8 + i];
#pragma unroll
            for (int j = 0; j < 8; ++j) {
                float m = u[0][j] - r[0];
#pragma unroll
                for (int i = 1; i < 8; ++i) m = fmaxf(m, u[i][j] - r[i]);
                float s0 = 0.f, s1 = 0.f;
#pragma unroll
                for (int i = 0; i < 8; i += 2) {
                    s0 += fexp2(u[i][j] - r[i] - m);
                    s1 += fexp2(u[i+1][j] - r[i+1] - m);
                }
                sm[j] = m; ss[j] = s0 + s1;
            }
        } else {
            float c[8];
#pragma unroll
            for (int j = 0; j < 8; ++j) c[j] = Cl[tb*8 + j];
#pragma unroll
            for (int i = 0; i < 8; ++i) {
                float m = u[i][0] - c[0];
#pragma unroll
                for (int j = 1; j < 8; ++j) m = fmaxf(m, u[i][j] - c[j]);
                float s0 = 0.f, s1 = 0.f;
#pragma unroll
                for (int j = 0; j < 8; j += 2) {
                    s0 += fexp2(u[i][j] - c[j] - m);
                    s1 += fexp2(u[i][j+1] - c[j+1] - m);
                }
                sm[i] = m; ss[i] = s0 + s1;
            }
        }
        {
            float* mrow = even ? &pm[ta][tb*8] : &pm[tb][ta*8];
            float* srow = even ? &ps[ta][tb*8] : &ps[tb][ta*8];
            ((float4*)mrow)[0] = make_float4(sm[0], sm[1], sm[2], sm[3]);
            ((float4*)mrow)[1] = make_float4(sm[4], sm[5], sm[6], sm[7]);
            ((float4*)srow)[0] = make_float4(ss[0], ss[1], ss[2], ss[3]);
            ((float4*)srow)[1] = make_float4(ss[4], ss[5], ss[6], ss[7]);
        }
        __syncthreads();
        float M = pm[sub*8][line4];
        float S = ps[sub*8][line4];
#pragma unroll
        for (int k = 1; k < 8; ++k) {
            float m2 = pm[sub*8 + k][line4];
            float s2 = ps[sub*8 + k][line4];
            float nm = fmaxf(M, m2);
            S = S * fexp2(M - nm) + s2 * fexp2(m2 - nm);
            M = nm;
        }
#pragma unroll
        for (int d = 1; d <= 2; d <<= 1) {
            float m2 = __shfl_xor(M, d);
            float s2 = __shfl_xor(S, d);
            float nm = fmaxf(M, m2);
            S = S * fexp2(M - nm) + s2 * fexp2(m2 - nm);
            M = nm;
        }
        if (sub == 0) {
            float l = M + flog2(S);
            if (even) Cl[line4] = l; else Rl[line4] = l;
        }
        __syncthreads();
    }

    // ---- iters 2..19: previous-offset shift, single pass, sum-only merge ---
#pragma unroll 1
    for (int it = 2; it < 20; ++it) {
        const bool even = (it & 1) == 0;
        float r[8], c[8], ss[8];
#pragma unroll
        for (int i = 0; i < 8; ++i) r[i] = Rl[ta*8 + i];
#pragma unroll
        for (int j = 0; j < 8; ++j) c[j] = Cl[tb*8 + j];
        if (even) {
#pragma unroll
            for (int j = 0; j < 8; ++j) {
                float s0 = 0.f, s1 = 0.f;
#pragma unroll
                for (int i = 0; i < 8; i += 2) {
                    s0 += fexp2(u[i][j] - r[i] - c[j]);
                    s1 += fexp2(u[i+1][j] - r[i+1] - c[j]);
                }
                ss[j] = s0 + s1;
            }
        } else {
#pragma unroll
            for (int i = 0; i < 8; ++i) {
                float s0 = 0.f, s1 = 0.f;
#pragma unroll
                for (int j = 0; j < 8; j += 2) {
                    s0 += fexp2(u[i][j] - c[j] - r[i]);
                    s1 += fexp2(u[i][j+1] - c[j+1] - r[i]);
                }
                ss[i] = s0 + s1;
            }
        }
        {
            float* srow = even ? &ps[ta][tb*8] : &ps[tb][ta*8];
            ((float4*)srow)[0] = make_float4(ss[0], ss[1], ss[2], ss[3]);
            ((float4*)srow)[1] = make_float4(ss[4], ss[5], ss[6], ss[7]);
        }
        __syncthreads();
        float S = 0.f;
#pragma unroll
        for (int k = 0; k < 8; ++k) S += ps[sub*8 + k][line4];
        S += __shfl_xor(S, 1);
        S += __shfl_xor(S, 2);
        if (sub == 0) {
            float d = flog2(S);
            if (even) Cl[line4] += d; else Rl[line4] += d;
        }
        __syncthreads();
    }

    float r[8], c[8];
#pragma unroll
    for (int i = 0; i < 8; ++i) r[i] = Rl[ta*8 + i];
#pragma unroll
    for (int j = 0; j < 8; ++j) c[j] = Cl[tb*8 + j];
#pragma unroll
    for (int i = 0; i < 8; ++i) {
        int a = ta*8 + i;
#pragma unroll
        for (int j = 0; j < 8; ++j) {
            out[((size_t)(a*256 + tb*8 + j) << 6) + 63] =
                fexp2(u[i][j] - r[i] - c[j]);
        }
    }
}

extern "C" void kernel_launch(void* const* d_in, const int* in_sizes, int n_in,
                              void* d_out, int out_size, void* d_ws, size_t ws_size,
                              hipStream_t stream)
{
    const float* K_value = (const float*)d_in[0];
    const int*   K_index = (const int*)d_in[1];
    const float* A_value = (const float*)d_in[2];
    const int*   A_index = (const int*)d_in[3];
    const float* x   = (const float*)d_in[4];
    const float* Wn1 = (const float*)d_in[5];
    const float* bn1 = (const float*)d_in[6];
    const float* Wn2 = (const float*)d_in[7];
    const float* bn2 = (const float*)d_in[8];
    const float* Ws1 = (const float*)d_in[9];
    const float* bs1 = (const float*)d_in[10];
    const float* Ws2 = (const float*)d_in[11];
    const float* bs2 = (const float*)d_in[12];
    const float* Wc  = (const float*)d_in[13];
    const float* bc  = (const float*)d_in[14];

    int nnzK = in_sizes[0];
    int nnzA = in_sizes[2];
    int n    = in_sizes[4] / FI;   // 65536

    const int* rowsK = K_index;  const int* colsK = K_index + nnzK;
    const int* rowsA = A_index;  const int* colsA = A_index + nnzA;

    float* outf = (float*)d_out;
    char*  ws   = (char*)d_ws;
    float* bufA = (float*)ws;                         // 16MB: x1, later x2
    float* x3   = bufA + (size_t)n * FP;              // n floats (tables aliased
    int*   tbl  = (int*)x3;                           //  during build phase)
    int*   cntK = tbl;          int* cntA = tbl + 256;
    int*   bstK = tbl + 512;    int* gcrK = tbl + 772;
    int*   bstA = tbl + 1032;   int* gcrA = tbl + 1292;
    int*   ptrKf = (int*)(x3 + n);                    // n ints
    int*   ptrAf = ptrKf + n;                         // n ints
    int2*  sdatK = (int2*)(ptrAf + n);                // nnzK entries
    int2*  sdatA = sdatK + nnzK;                      // nnzA entries

    size_t need1 = ((size_t)n * FP + 3 * (size_t)n) * 4 + ((size_t)nnzK + nnzA) * 8;
    size_t need2 = ((size_t)n * FP + 2 * (size_t)n) * 4 + (size_t)nnzK * 8;

    if (ws_size >= need1 && n == 65536 && nnzK <= (1 << 24) && nnzA <= (1 << 24)) {
        // ---- tier 1: fused-launch bucket + LDS row-sort + high-TLP gather --
        int nbK = (nnzK + CHUNK - 1) / CHUNK;
        int nbA = (nnzA + CHUNK - 1) / CHUNK;
        (void)hipMemsetAsync(cntK, 0, 512 * 4, stream);
        // mlp (256 blocks) || hist (512 blocks), one grid
        k_mlp_hist<<<(n >> 8) + 512, 256, 0, stream>>>(
            x, Wn1, bn1, Wn2, bn2, bufA, n, rowsK, rowsA, cntK, cntA, nnzK, nnzA);
        k_scan256<<<1, 256, 0, stream>>>(cntK, cntA, bstK, gcrK, bstA, gcrA);
        kb_bucket2<<<nbK + nbA, 256, 0, stream>>>(
            rowsK, colsK, K_value, gcrK, sdatK, nnzK, nbK,
            rowsA, colsA, A_value, gcrA, sdatA, nnzA);
        kb_sort2<<<512, 256, 0, stream>>>(
            bstK, sdatK, ptrKf, (int2*)outf,
            bstA, sdatA, ptrAf, (int2*)outf + nnzK);
        // Wx(d_out) = K @ x1 ; x2(bufA) = A @ Wx
        kb_gather<<<(n + 3) / 4, 256, 0, stream>>>(ptrKf, sdatK, bufA, outf, n);
        kb_gather<<<(n + 3) / 4, 256, 0, stream>>>(ptrAf, sdatA, outf, bufA, n);
    } else if (ws_size >= need2 && n == 65536) {
        // ---- tier 2: sequential CSR (proven) ----
        k_mlp_n<<<(n + 255) / 256, 256, 0, stream>>>(x, Wn1, bn1, Wn2, bn2, bufA, n);
        int* ptrK = (int*)(x3 + n);
        int2* sdat2 = (int2*)(ptrK + n);
        (void)hipMemsetAsync(ptrK, 0, (size_t)n * 4, stream);
        k_hist<<<2048, 256, 0, stream>>>(rowsK, ptrK, nnzK);
        k_scan2<<<1, 1024, 0, stream>>>(ptrK, ptrK);
        k_scatter<<<2048, 256, 0, stream>>>(rowsK, colsK, K_value, ptrK, sdat2, nnzK);
        k_gather<<<(n + 3) / 4, 256, 0, stream>>>(ptrK, sdat2, bufA, outf, n);
        (void)hipMemsetAsync(ptrK, 0, (size_t)n * 4, stream);
        k_hist<<<2048, 256, 0, stream>>>(rowsA, ptrK, nnzA);
        k_scan2<<<1, 1024, 0, stream>>>(ptrK, ptrK);
        k_scatter<<<2048, 256, 0, stream>>>(rowsA, colsA, A_value, ptrK, sdat2, nnzA);
        k_gather<<<(n + 3) / 4, 256, 0, stream>>>(ptrK, sdat2, outf, bufA, n);
    } else {
        // ---- tier 3: atomic scatter fallback ----
        k_mlp_n<<<(n + 255) / 256, 256, 0, stream>>>(x, Wn1, bn1, Wn2, bn2, bufA, n);
        (void)hipMemsetAsync(outf, 0, (size_t)n * FP * 4, stream);
        int blocks1 = (nnzK + 4 * NZPW - 1) / (4 * NZPW);
        k_spmm<<<blocks1, 256, 0, stream>>>(rowsK, colsK, K_value, bufA, outf, nnzK);
        (void)hipMemsetAsync(bufA, 0, (size_t)n * FP * 4, stream);
        int blocks2 = (nnzA + 4 * NZPW - 1) / (4 * NZPW);
        k_spmm<<<blocks2, 256, 0, stream>>>(rowsA, colsA, A_value, outf, bufA, nnzA);
    }

    // combine: self-MLP + x2(bufA), write out[:, :63], classifier -> x3
    k_combine<<<(n + 255) / 256, 256, 0, stream>>>(x, Ws1, bs1, Ws2, bs2, Wc, bc,
                                                   bufA, outf, x3, n);
    // sinkhorn -> out[:, 63]
    k_sinkhorn<<<1, 1024, 0, stream>>>(x3, outf);
}